// Round 15
// baseline (134.604 us; speedup 1.0000x reference)
//
#include <hip/hip_runtime.h>
#include <hip/hip_bf16.h>
#include <math.h>

#define T_SEQ 1024
#define LOG2_10000 13.287712379549449f

typedef unsigned short u16;
typedef unsigned int u32;
typedef __attribute__((ext_vector_type(8))) short bf16x8;
typedef __attribute__((ext_vector_type(4))) float f32x4;

__device__ __forceinline__ void gload16(const u16* g, const u16* s) {
  __builtin_amdgcn_global_load_lds(
      (const __attribute__((address_space(1))) void*)g,
      (__attribute__((address_space(3))) void*)s, 16, 0, 0);
}

__device__ __forceinline__ u16 f2bf(float x) {
  __hip_bfloat16 h = __float2bfloat16(x);
  return *reinterpret_cast<u16*>(&h);
}
__device__ __forceinline__ float bf2f(u16 x) {
  __hip_bfloat16 h = *reinterpret_cast<__hip_bfloat16*>(&x);
  return __bfloat162float(h);
}

// ------------------------------------------------------------------
// transpose helper: W[K=1024][N] fp32 -> Wt[N][1024] bf16, one 32x32 tile
// ------------------------------------------------------------------
__device__ __forceinline__ void transpose_step(
    const float* __restrict__ W, u16* __restrict__ Wt, int N, int nbx,
    int local, int t, float (*tile)[33]) {
  int bx = local % nbx, by = local / nbx;
  int n0 = bx * 32, k0 = by * 32;
  int r = t >> 3, c4 = (t & 7) * 4;
  float4 v = *reinterpret_cast<const float4*>(&W[(size_t)(k0 + r) * N + n0 + c4]);
  tile[r][c4 + 0] = v.x;
  tile[r][c4 + 1] = v.y;
  tile[r][c4 + 2] = v.z;
  tile[r][c4 + 3] = v.w;
  __syncthreads();
  u16 o[4];
#pragma unroll
  for (int i = 0; i < 4; ++i) o[i] = f2bf(tile[c4 + i][r]);
  *reinterpret_cast<uint2*>(&Wt[(size_t)(n0 + r) * 1024 + k0 + c4]) =
      *reinterpret_cast<const uint2*>(o);
}

// ------------------------------------------------------------------
// fused prep: rope tables | X cvt | WQ,WV,WK -> WQVKt[9216][1024] |
//             WO -> WOt | bias concat [bQ;bV;bK]
// ------------------------------------------------------------------
__global__ __launch_bounds__(256) void prep_kernel(
    const float* __restrict__ X, const float* __restrict__ WQ,
    const float* __restrict__ WK, const float* __restrict__ WV,
    const float* __restrict__ WO, const float* __restrict__ bQ,
    const float* __restrict__ bV, const float* __restrict__ bK,
    u16* __restrict__ Xb, u16* __restrict__ WQVKt, u16* __restrict__ WOt,
    float* __restrict__ bQVK, float* __restrict__ ctab, float* __restrict__ stab)
{
  __shared__ float tile[32][33];
  const int blk = blockIdx.x, t = threadIdx.x;
  if (blk < 128) {                       // rope tables (32768)
    int id = blk * 256 + t;
    int tt = id >> 5, p = id & 31;
    float invf = exp2f(-LOG2_10000 * (float)(2 * p) * (1.0f / 64.0f));
    float ang = (float)tt * invf;
    float sn, cs;
    sincosf(ang, &sn, &cs);
    ctab[id] = cs;
    stab[id] = sn;
  } else if (blk < 1152) {               // X fp32 -> bf16 (262144 x8)
    int i = (blk - 128) * 256 + t;
    float4 a = reinterpret_cast<const float4*>(X)[2 * i];
    float4 b = reinterpret_cast<const float4*>(X)[2 * i + 1];
    u16 o[8] = {f2bf(a.x), f2bf(a.y), f2bf(a.z), f2bf(a.w),
                f2bf(b.x), f2bf(b.y), f2bf(b.z), f2bf(b.w)};
    reinterpret_cast<uint4*>(Xb)[i] = *reinterpret_cast<const uint4*>(o);
  } else if (blk < 5248) {
    transpose_step(WQ, WQVKt, 4096, 128, blk - 1152, t, tile);
  } else if (blk < 9344) {
    transpose_step(WV, WQVKt + (size_t)4096 * 1024, 4096, 128, blk - 5248, t, tile);
  } else if (blk < 10368) {
    transpose_step(WK, WQVKt + (size_t)8192 * 1024, 1024, 32, blk - 9344, t, tile);
  } else if (blk < 11392) {
    transpose_step(WO, WOt, 1024, 32, blk - 10368, t, tile);
  } else {                               // bias concat (9216)
    int id = (blk - 11392) * 256 + t;
    if (id < 9216)
      bQVK[id] = (id < 4096) ? bQ[id] : (id < 8192) ? bV[id - 4096] : bK[id - 8192];
  }
}

// ------------------------------------------------------------------
// QV GEMM (R8/R11-proven): 256x256 tile, BK=32, 4 LDS slots,
// 2-tile-deep prefetch, counted vmcnt(8), ONE barrier per K-tile,
// swizzle chunk^=(row>>1)&3 (2-way = free), setprio MFMA.
// Grid 256 = 1/CU, 2D XCD chunking (B-slice 4MB L2-fit).
// ------------------------------------------------------------------
__global__ __launch_bounds__(512, 1) void gemm_qv_kernel(
    const u16* __restrict__ Ab, const u16* __restrict__ Bt,
    const float* __restrict__ bias, u16* __restrict__ Cqv)
{
  __shared__ __align__(16) u16 sA[4][256 * 32];
  __shared__ __align__(16) u16 sB[4][256 * 32];

  const int tid = threadIdx.x;
  const int lane = tid & 63;
  const int w = tid >> 6;
  const int wm = w >> 2, wn = w & 3;
  const int l15 = lane & 15, l4 = lane >> 4;

  const int orig = blockIdx.x;          // 256
  const int xcd = orig & 7, j = orig >> 3;
  const int by = (xcd >> 2) * 4 + (j >> 3);
  const int bx = (xcd & 3) * 8 + (j & 7);
  const int m0 = by * 256, n0 = bx * 256;

  const int r0s = tid >> 2,         c0s = tid & 3;
  const int r1s = (512 + tid) >> 2, c1s = (512 + tid) & 3;
  const int sc0 = c0s ^ ((r0s >> 1) & 3);
  const int sc1 = c1s ^ ((r1s >> 1) & 3);
  const u16* aA0 = Ab + (size_t)(m0 + r0s) * 1024 + 8 * sc0;
  const u16* aA1 = Ab + (size_t)(m0 + r1s) * 1024 + 8 * sc1;
  const u16* aB0 = Bt + (size_t)(n0 + r0s) * 1024 + 8 * sc0;
  const u16* aB1 = Bt + (size_t)(n0 + r1s) * 1024 + 8 * sc1;

  const int cp = l4 ^ ((l15 >> 1) & 3);

  f32x4 acc[8][4];
#pragma unroll
  for (int i = 0; i < 8; ++i)
#pragma unroll
    for (int jn = 0; jn < 4; ++jn) acc[i][jn] = (f32x4){0.f, 0.f, 0.f, 0.f};

#define STAGE32(t)                                                             \
  {                                                                            \
    const int sl = (t) & 3;                                                    \
    const int ko = (t) * 32;                                                   \
    gload16(aA0 + ko, &sA[sl][tid * 8]);                                       \
    gload16(aA1 + ko, &sA[sl][4096 + tid * 8]);                                \
    gload16(aB0 + ko, &sB[sl][tid * 8]);                                       \
    gload16(aB1 + ko, &sB[sl][4096 + tid * 8]);                                \
  }

  STAGE32(0);
  STAGE32(1);
#pragma unroll 1
  for (int t = 0; t < 32; ++t) {
    if (t + 2 < 32) {
      STAGE32(t + 2);
      asm volatile("s_waitcnt vmcnt(8)" ::: "memory");
    } else if (t + 1 < 32) {
      asm volatile("s_waitcnt vmcnt(4)" ::: "memory");
    } else {
      asm volatile("s_waitcnt vmcnt(0)" ::: "memory");
    }
    __builtin_amdgcn_sched_barrier(0);
    __builtin_amdgcn_s_barrier();
    __builtin_amdgcn_sched_barrier(0);

    const u16* tA = sA[t & 3];
    const u16* tB = sB[t & 3];

    bf16x8 bf[4];
#pragma unroll
    for (int n = 0; n < 4; ++n) {
      int row = wn * 64 + n * 16 + l15;
      bf[n] = *reinterpret_cast<const bf16x8*>(&tB[row * 32 + cp * 8]);
    }
    bf16x8 af[8];
#pragma unroll
    for (int m = 0; m < 8; ++m) {
      int row = wm * 128 + m * 16 + l15;
      af[m] = *reinterpret_cast<const bf16x8*>(&tA[row * 32 + cp * 8]);
    }
    __builtin_amdgcn_s_setprio(1);
#pragma unroll
    for (int m = 0; m < 8; ++m)
#pragma unroll
      for (int n = 0; n < 4; ++n)
        acc[m][n] = __builtin_amdgcn_mfma_f32_16x16x32_bf16(
            af[m], bf[n], acc[m][n], 0, 0, 0);
    __builtin_amdgcn_s_setprio(0);
    // no trailing barrier: slot (t&3) next written by a STAGE issued only
    // after two subsequent barriers -> WAR-safe.
  }
#undef STAGE32

#pragma unroll
  for (int n = 0; n < 4; ++n) {
    int col = n0 + wn * 64 + n * 16 + l15;
    float bv = bias[col];
#pragma unroll
    for (int mf = 0; mf < 8; ++mf) {
#pragma unroll
      for (int r = 0; r < 4; ++r) {
        int row = m0 + wm * 128 + mf * 16 + l4 * 4 + r;
        Cqv[(size_t)row * 8192 + col] = f2bf(acc[mf][n][r] + bv);
      }
    }
  }
}

// ------------------------------------------------------------------
// 64x64-tile bf16 MFMA GEMM, BK=64, double-buffered, ONE raw barrier
// per K-step + counted vmcnt(4). LDS rows 128B with chunk^(row&7)
// swizzle (2-way bank aliasing = free).
// ------------------------------------------------------------------
template <bool BF16OUT>
__global__ __launch_bounds__(256) void gemm64_kernel(
    const u16* __restrict__ Ab, const u16* __restrict__ Bt,
    const float* __restrict__ bias, void* __restrict__ Cv,
    int M, int N, int K)
{
  __shared__ __align__(16) u16 sA[2][64 * 64];
  __shared__ __align__(16) u16 sB[2][64 * 64];
  const int tid = threadIdx.x;
  const int lane = tid & 63;
  const int wv = tid >> 6;
  const int wm = wv >> 1, wn = wv & 1;
  const int l15 = lane & 15, l4 = lane >> 4;
  const int m0 = blockIdx.y * 64, n0 = blockIdx.x * 64;

  f32x4 acc[2][2];
#pragma unroll
  for (int i = 0; i < 2; ++i)
#pragma unroll
    for (int j = 0; j < 2; ++j) acc[i][j] = (f32x4){0.f, 0.f, 0.f, 0.f};

  const int r0s = tid >> 3,         c0s = tid & 7;
  const int r1s = (256 + tid) >> 3, c1s = (256 + tid) & 7;
  const int sc0 = c0s ^ (r0s & 7);
  const int sc1 = c1s ^ (r1s & 7);
  const u16* aA0 = Ab + (size_t)(m0 + r0s) * K + 8 * sc0;
  const u16* aA1 = Ab + (size_t)(m0 + r1s) * K + 8 * sc1;
  const u16* aB0 = Bt + (size_t)(n0 + r0s) * K + 8 * sc0;
  const u16* aB1 = Bt + (size_t)(n0 + r1s) * K + 8 * sc1;

  gload16(aA0, &sA[0][tid * 8]);
  gload16(aA1, &sA[0][2048 + tid * 8]);
  gload16(aB0, &sB[0][tid * 8]);
  gload16(aB1, &sB[0][2048 + tid * 8]);

  const int niter = K >> 6;
#pragma unroll 1
  for (int it = 0; it < niter; ++it) {
    const int buf = it & 1;
    __builtin_amdgcn_s_barrier();
    if (it + 1 < niter) {
      const int ko = (it + 1) * 64;
      gload16(aA0 + ko, &sA[buf ^ 1][tid * 8]);
      gload16(aA1 + ko, &sA[buf ^ 1][2048 + tid * 8]);
      gload16(aB0 + ko, &sB[buf ^ 1][tid * 8]);
      gload16(aB1 + ko, &sB[buf ^ 1][2048 + tid * 8]);
      asm volatile("s_waitcnt vmcnt(4)" ::: "memory");
    } else {
      asm volatile("s_waitcnt vmcnt(0)" ::: "memory");
    }
    __builtin_amdgcn_sched_barrier(0);
    bf16x8 af[2][2], bfv[2][2];
#pragma unroll
    for (int kk = 0; kk < 2; ++kk) {
#pragma unroll
      for (int mi = 0; mi < 2; ++mi) {
        int row = wm * 32 + mi * 16 + l15;
        int cs = (kk * 4 + l4) ^ (row & 7);
        af[mi][kk] = *reinterpret_cast<const bf16x8*>(&sA[buf][row * 64 + cs * 8]);
      }
#pragma unroll
      for (int ni = 0; ni < 2; ++ni) {
        int row = wn * 32 + ni * 16 + l15;
        int cs = (kk * 4 + l4) ^ (row & 7);
        bfv[ni][kk] = *reinterpret_cast<const bf16x8*>(&sB[buf][row * 64 + cs * 8]);
      }
    }
#pragma unroll
    for (int kk = 0; kk < 2; ++kk)
#pragma unroll
      for (int mi = 0; mi < 2; ++mi)
#pragma unroll
        for (int ni = 0; ni < 2; ++ni)
          acc[mi][ni] = __builtin_amdgcn_mfma_f32_16x16x32_bf16(
              af[mi][kk], bfv[ni][kk], acc[mi][ni], 0, 0, 0);
  }

#pragma unroll
  for (int mi = 0; mi < 2; ++mi)
#pragma unroll
    for (int ni = 0; ni < 2; ++ni) {
      int col = n0 + wn * 32 + ni * 16 + l15;
      float bv = bias[col];
#pragma unroll
      for (int r = 0; r < 4; ++r) {
        int row = m0 + wm * 32 + mi * 16 + l4 * 4 + r;
        float val = acc[mi][ni][r] + bv;
        size_t idx = (size_t)row * N + col;
        if (BF16OUT) ((u16*)Cv)[idx] = f2bf(val);
        else ((float*)Cv)[idx] = val;
      }
    }
}

// ------------------------------------------------------------------
// merged: q/k transform (blocks < 20480) + vsum partials (128 blocks).
// ------------------------------------------------------------------
__global__ __launch_bounds__(256) void qkvt_kernel(
    u16* __restrict__ QVbf, u16* __restrict__ Kbf,
    const float* __restrict__ ctab, const float* __restrict__ stab,
    float* __restrict__ part)
{
  const int blk = blockIdx.x;
  if (blk < 20480) {
    const int rid  = blk * 8 + (threadIdx.x >> 5);
    const int lane = threadIdx.x & 63;
    const int p    = lane & 31;
    const int gb   = lane & 32;

    u16* row;
    int t;
    const bool isQ = rid < 131072;
    if (isQ) {
      int h = rid & 63, bt = rid >> 6;
      t = bt & 1023;
      row = QVbf + (size_t)bt * 8192 + h * 64;
    } else {
      int r2 = rid - 131072;
      int hsL = r2 & 15, bt = r2 >> 4;
      t = bt & 1023;
      row = Kbf + (size_t)bt * 1024 + hsL * 64;
    }

    u32 v = reinterpret_cast<const u32*>(row)[p];
    float x1 = bf2f((u16)v), x2 = bf2f((u16)(v >> 16));
    float cs = ctab[t * 32 + p], sn = stab[t * 32 + p];

    float o_lo, o_hi;
    if (isQ) {
      float ss = x1 * x1 + x2 * x2;
      ss += __shfl_xor(ss, 1, 64);
      ss += __shfl_xor(ss, 2, 64);
      ss += __shfl_xor(ss, 4, 64);
      ss += __shfl_xor(ss, 8, 64);
      ss += __shfl_xor(ss, 16, 64);
      float rs = rsqrtf(ss * (1.0f / 64.0f) + 1.1920929e-7f);
      float xn1 = x1 * rs, xn2 = x2 * rs;
      o_lo = xn1 * cs - xn2 * sn;
      o_hi = xn1 * sn + xn2 * cs;
    } else {
      float xr1 = x1 * cs - x2 * sn;
      float xr2 = x1 * sn + x2 * cs;
      float ss = xr1 * xr1 + xr2 * xr2;
      ss += __shfl_xor(ss, 1, 64);
      ss += __shfl_xor(ss, 2, 64);
      ss += __shfl_xor(ss, 4, 64);
      ss += __shfl_xor(ss, 8, 64);
      ss += __shfl_xor(ss, 16, 64);
      float rs = rsqrtf(ss);
      o_lo = xr1 * rs;
      o_hi = xr2 * rs;
    }

    int m = (2 * p) & 31;
    float slo0 = __shfl(o_lo, gb + m, 64);
    float slo1 = __shfl(o_lo, gb + m + 1, 64);
    float shi0 = __shfl(o_hi, gb + m, 64);
    float shi1 = __shfl(o_hi, gb + m + 1, 64);
    float e0 = (p < 16) ? slo0 : shi0;
    float e1 = (p < 16) ? slo1 : shi1;
    reinterpret_cast<u32*>(row)[p] = (u32)f2bf(e0) | ((u32)f2bf(e1) << 16);
  } else {
    int vb = blk - 20480;               // 0..127: b*64 + ch
    int b = vb >> 6, ch = vb & 63;
    const u16* base = QVbf + (size_t)(b * 1024 + ch * 16) * 8192 + 4096;
#pragma unroll
    for (int g = 0; g < 2; ++g) {
      int c0 = (threadIdx.x + g * 256) * 8;
      float s[8] = {0.f, 0.f, 0.f, 0.f, 0.f, 0.f, 0.f, 0.f};
#pragma unroll 4
      for (int r = 0; r < 16; ++r) {
        bf16x8 v = *reinterpret_cast<const bf16x8*>(&base[(size_t)r * 8192 + c0]);
#pragma unroll
        for (int e = 0; e < 8; ++e) s[e] += bf2f((u16)v[e]);
      }
      float* dst = &part[(size_t)vb * 4096 + c0];
#pragma unroll
      for (int e = 0; e < 8; ++e) dst[e] = s[e];
    }
  }
}

__global__ __launch_bounds__(256) void vsum_reduce_kernel(
    const float* __restrict__ part, float* __restrict__ Vsum) {
  int id = blockIdx.x * 256 + threadIdx.x;  // 8192
  int b = id >> 12, n = id & 4095;
  float s = 0.f;
#pragma unroll 8
  for (int ch = 0; ch < 64; ++ch) s += part[(size_t)(b * 64 + ch) * 4096 + n];
  Vsum[id] = s;
}

// ------------------------------------------------------------------
// MFMA banded attention, QBLK=128, 8 waves (512 thr), 2-phase
// double-buffered K/V pipeline (same proven barrier/vmcnt skeleton).
// Wave wv owns q rows [wv*16, wv*16+16). 19 chunks per 128 queries
// vs 30 before (-37% staging).  LDS 64KB -> 2 blocks/CU.
// ------------------------------------------------------------------
__global__ __launch_bounds__(512) void attn_mfma_kernel(
    const u16* __restrict__ Qv, const u16* __restrict__ Kb,
    const float* __restrict__ Vsum, const float* __restrict__ sink,
    const float* __restrict__ vnull, u16* __restrict__ mctxb)
{
  __shared__ __align__(16) u16 sQ[128 * 64];
  __shared__ __align__(16) u16 sK[2][64 * 64];
  __shared__ __align__(16) u16 sVt[2][64 * 64];
  __shared__ __align__(16) u16 sP[128 * 64];

  int blk = blockIdx.x;                 // 256 = b(2) * hs(16) * qt(8)
  blk = (blk & 7) * 32 + (blk >> 3);    // XCD-chunked (256%8==0, bijective)
  const int qt  = blk & 7;
  const int hs  = (blk >> 3) & 15;
  const int b   = blk >> 7;
  const int qt0 = qt * 128;

  const int tid  = threadIdx.x;
  const int lane = tid & 63;
  const int wv   = tid >> 6;            // 0..7
  const int l15  = lane & 15;
  const int l4   = lane >> 4;
  const int qr0  = tid >> 3, qi0 = tid & 7;   // Q/K staging decode
  const int vjp  = tid & 31, vdg = (tid >> 5) & 7;
  const bool vact = tid < 256;          // V staging threads
  const int qrow = wv * 16 + l15;

  constexpr int HCFG[4] = {16, 128, 128, 512};
  constexpr int GCFG[4] = {0, 16, 0, 144};

  f32x4 macc[4];
#pragma unroll
  for (int i = 0; i < 4; ++i) macc[i] = (f32x4){0.f, 0.f, 0.f, 0.f};

#pragma unroll 1
  for (int br = 0; br < 4; ++br) {
    const int h = br * 16 + hs;
    const int hmax = HCFG[br], g = GCFG[br];
    int klo = qt0 - (hmax - 1); if (klo < 0) klo = 0;
    int khi = qt0 + 127 - g;    if (khi > 1023) khi = 1023;
    const int nc = (khi >= klo) ? ((khi - klo) / 64 + 1) : 0;

    // stage Q: 128x64 = 1024 chunks; thread does chunks tid, tid+512
    gload16(Qv + (size_t)(b * 1024 + qt0 + qr0) * 8192 + h * 64 + 8 * (qi0 ^ (qr0 & 7)),
            sQ + (size_t)wv * 512);
    gload16(Qv + (size_t)(b * 1024 + qt0 + 64 + qr0) * 8192 + h * 64 + 8 * (qi0 ^ (qr0 & 7)),
            sQ + 4096 + (size_t)wv * 512);
    bf16x8 va, vb;
    if (nc > 0) {
      int ja0 = klo + qr0; if (ja0 > 1023) ja0 = 1023;   // K: 512 chunks, 1/thread
      gload16(Kb + (size_t)(b * 1024 + ja0) * 1024 + hs * 64 + 8 * (qi0 ^ (qr0 & 7)),
              sK[0] + (size_t)wv * 512);
      if (vact) {
        int jva = klo + 2 * vjp, jvb = jva + 1;
        if (jva > 1023) jva = 1023;
        if (jvb > 1023) jvb = 1023;
        va = *reinterpret_cast<const bf16x8*>(
            &Qv[(size_t)(b * 1024 + jva) * 8192 + 4096 + h * 64 + vdg * 8]);
        vb = *reinterpret_cast<const bf16x8*>(
            &Qv[(size_t)(b * 1024 + jvb) * 8192 + 4096 + h * 64 + vdg * 8]);
      }
    }
    asm volatile("s_waitcnt vmcnt(0)" ::: "memory");
    __builtin_amdgcn_sched_barrier(0);
    if (nc > 0 && vact) {
#pragma unroll
      for (int e = 0; e < 8; ++e) {
        int d = vdg * 8 + e;
        u32 pack = (u32)(u16)va[e] | ((u32)(u16)vb[e] << 16);
        *reinterpret_cast<u32*>(
            (char*)sVt[0] + d * 128 + ((4 * vjp) ^ ((d & 7) << 4))) = pack;
      }
    }
    asm volatile("s_waitcnt lgkmcnt(0)" ::: "memory");
    __builtin_amdgcn_sched_barrier(0);
    __builtin_amdgcn_s_barrier();

    bf16x8 afQ[2];
#pragma unroll
    for (int kh = 0; kh < 2; ++kh) {
      int cs = (4 * kh + l4) ^ (l15 & 7);
      afQ[kh] = *reinterpret_cast<const bf16x8*>(&sQ[qrow * 64 + cs * 8]);
    }

    f32x4 outv[4];
#pragma unroll
    for (int i = 0; i < 4; ++i) outv[i] = (f32x4){0.f, 0.f, 0.f, 0.f};
    float zacc[4] = {0.f, 0.f, 0.f, 0.f};

    int buf = 0;
#pragma unroll 1
    for (int c = 0; c < nc; ++c) {
      const int j0 = klo + c * 64;
      const bool nxt = (c + 1 < nc);
      if (nxt) {
        int j0n = j0 + 64;
        int ja0 = j0n + qr0; if (ja0 > 1023) ja0 = 1023;
        gload16(Kb + (size_t)(b * 1024 + ja0) * 1024 + hs * 64 + 8 * (qi0 ^ (qr0 & 7)),
                sK[buf ^ 1] + (size_t)wv * 512);
        if (vact) {
          int jva = j0n + 2 * vjp, jvb = jva + 1;
          if (jva > 1023) jva = 1023;
          if (jvb > 1023) jvb = 1023;
          va = *reinterpret_cast<const bf16x8*>(
              &Qv[(size_t)(b * 1024 + jva) * 8192 + 4096 + h * 64 + vdg * 8]);
          vb = *reinterpret_cast<const bf16x8*>(
              &Qv[(size_t)(b * 1024 + jvb) * 8192 + 4096 + h * 64 + vdg * 8]);
        }
      }
      f32x4 sfr[4];
      __builtin_amdgcn_s_setprio(1);
#pragma unroll
      for (int jt = 0; jt < 4; ++jt) {
        int krow = jt * 16 + l15;
        f32x4 acc = (f32x4){0.f, 0.f, 0.f, 0.f};
#pragma unroll
        for (int kh = 0; kh < 2; ++kh) {
          int cs = (4 * kh + l4) ^ (l15 & 7);
          bf16x8 bk = *reinterpret_cast<const bf16x8*>(&sK[buf][krow * 64 + cs * 8]);
          acc = __builtin_amdgcn_mfma_f32_16x16x32_bf16(afQ[kh], bk, acc, 0, 0, 0);
        }
        sfr[jt] = acc;
      }
      __builtin_amdgcn_s_setprio(0);
#pragma unroll
      for (int jt = 0; jt < 4; ++jt) {
        int jloc = jt * 16 + l15;
        int jabs = j0 + jloc;
#pragma unroll
        for (int r = 0; r < 4; ++r) {
          int q_r = wv * 16 + l4 * 4 + r;
          int dist = (qt0 + q_r) - jabs;
          bool inband = (dist >= g) & (dist < hmax) & (jabs < 1024);
          float pv = inband ? (__expf(sfr[jt][r]) - 1.0f) : 0.0f;
          zacc[r] += pv;
          *reinterpret_cast<u16*>(
              (char*)sP + q_r * 128 + ((2 * jloc) ^ ((q_r & 7) << 4))) = f2bf(pv);
        }
      }
      asm volatile("s_waitcnt lgkmcnt(0)" ::: "memory");
      __builtin_amdgcn_sched_barrier(0);
      bf16x8 afP[2];
#pragma unroll
      for (int kh = 0; kh < 2; ++kh) {
        int cs = (4 * kh + l4) ^ (l15 & 7);
        afP[kh] = *reinterpret_cast<const bf16x8*>(&sP[qrow * 64 + cs * 8]);
      }
      __builtin_amdgcn_s_setprio(1);
#pragma unroll
      for (int dt = 0; dt < 4; ++dt) {
        int drow = dt * 16 + l15;
#pragma unroll
        for (int kh = 0; kh < 2; ++kh) {
          int cs = (4 * kh + l4) ^ (l15 & 7);
          bf16x8 bv = *reinterpret_cast<const bf16x8*>(&sVt[buf][drow * 64 + cs * 8]);
          outv[dt] = __builtin_amdgcn_mfma_f32_16x16x32_bf16(afP[kh], bv, outv[dt], 0, 0, 0);
        }
      }
      __builtin_amdgcn_s_setprio(0);
      if (nxt && vact) {
#pragma unroll
        for (int e = 0; e < 8; ++e) {
          int d = vdg * 8 + e;
          u32 pack = (u32)(u16)va[e] | ((u32)(u16)vb[e] << 16);
          *reinterpret_cast<u32*>(
              (char*)sVt[buf ^ 1] + d * 128 + ((4 * vjp) ^ ((d & 7) << 4))) = pack;
        }
      }
      asm volatile("s_waitcnt vmcnt(0) lgkmcnt(0)" ::: "memory");
      __builtin_amdgcn_sched_barrier(0);
      __builtin_amdgcn_s_barrier();
      buf ^= 1;
    }

#pragma unroll
    for (int r = 0; r < 4; ++r) {
      zacc[r] += __shfl_xor(zacc[r], 1, 64);
      zacc[r] += __shfl_xor(zacc[r], 2, 64);
      zacc[r] += __shfl_xor(zacc[r], 4, 64);
      zacc[r] += __shfl_xor(zacc[r], 8, 64);
    }
    float es = __expf(tanhf(sink[h]));
#pragma unroll
    for (int dt = 0; dt < 4; ++dt) {
      int d = dt * 16 + l15;
      float vs = Vsum[(size_t)b * 4096 + h * 64 + d];
      float vn = vnull[h * 64 + d];
#pragma unroll
      for (int r = 0; r < 4; ++r) {
        float invZ = 1.0f / (1024.0f + zacc[r] + es);
        macc[dt][r] += (outv[dt][r] + vs + es * vn) * invZ;
      }
    }
  }

#pragma unroll
  for (int dt = 0; dt < 4; ++dt) {
#pragma unroll
    for (int r = 0; r < 4; ++r) {
      int q_r = wv * 16 + l4 * 4 + r;
      mctxb[(size_t)(b * 1024 + qt0 + q_r) * 1024 + hs * 64 + dt * 16 + l15] =
          f2bf(0.25f * macc[dt][r]);
    }
  }
}

extern "C" void kernel_launch(void* const* d_in, const int* in_sizes, int n_in,
                              void* d_out, int out_size, void* d_ws, size_t ws_size,
                              hipStream_t stream) {
  (void)in_sizes; (void)n_in; (void)out_size; (void)ws_size;
  const float* X    = (const float*)d_in[0];
  const float* WQ   = (const float*)d_in[1];
  const float* bQ   = (const float*)d_in[2];
  const float* WK   = (const float*)d_in[3];
  const float* bK   = (const float*)d_in[4];
  const float* WV   = (const float*)d_in[5];
  const float* bV   = (const float*)d_in[6];
  const float* WO   = (const float*)d_in[7];
  const float* bO   = (const float*)d_in[8];
  const float* sink = (const float*)d_in[9];
  const float* vnul = (const float*)d_in[10];
  float* Y = (float*)d_out;

  char* p = (char*)d_ws;
  u16*   Xb    = (u16*)p;   p += (size_t)2048 * 1024 * 2;   //  4 MB
  u16*   WQVKt = (u16*)p;   p += (size_t)9216 * 1024 * 2;   // 18 MB
  u16*   WOt   = (u16*)p;   p += (size_t)1024 * 1024 * 2;   //  2 MB
  u16*   QVbf  = (u16*)p;   p += (size_t)2048 * 8192 * 2;   // 32 MB
  u16*   Kbf   = (u16*)p;   p += (size_t)2048 * 1024 * 2;   //  4 MB
  u16*   mctxb = (u16*)p;   p += (size_t)2048 * 1024 * 2;   //  4 MB
  float* Vsum  = (float*)p; p += (size_t)2 * 4096 * 4;      // 32 KB
  float* vpart = (float*)p; p += (size_t)128 * 4096 * 4;    //  2 MB
  float* bQVK  = (float*)p; p += (size_t)9216 * 4;          //  36 KB
  float* ctab  = (float*)p; p += (size_t)32768 * 4;         // 128 KB
  float* stab  = (float*)p; p += (size_t)32768 * 4;         // 128 KB

  dim3 blk(256);
  prep_kernel<<<11428, blk, 0, stream>>>(X, WQ, WK, WV, WO, bQ, bV, bK,
                                         Xb, WQVKt, WOt, bQVK, ctab, stab);

  gemm_qv_kernel<<<256, dim3(512), 0, stream>>>(Xb, WQVKt, bQVK, QVbf);
  gemm64_kernel<true><<<dim3(16, 32), blk, 0, stream>>>(
      Xb, WQVKt + (size_t)8192 * 1024, bQVK + 8192, Kbf, 2048, 1024, 1024);

  qkvt_kernel<<<20608, blk, 0, stream>>>(QVbf, Kbf, ctab, stab, vpart);
  vsum_reduce_kernel<<<32, blk, 0, stream>>>(vpart, Vsum);

  attn_mfma_kernel<<<256, dim3(512), 0, stream>>>(QVbf, Kbf, Vsum, sink, vnul, mctxb);

  gemm64_kernel<false><<<dim3(16, 32), blk, 0, stream>>>(mctxb, WOt, bO, Y, 2048, 1024, 1024);
}

// Round 16
// 132.185 us; speedup vs baseline: 1.0183x; 1.0183x over previous
//
#include <hip/hip_runtime.h>
#include <hip/hip_bf16.h>
#include <math.h>

#define T_SEQ 1024
#define LOG2_10000 13.287712379549449f

typedef unsigned short u16;
typedef unsigned int u32;
typedef __attribute__((ext_vector_type(8))) short bf16x8;
typedef __attribute__((ext_vector_type(4))) float f32x4;

__device__ __forceinline__ void gload16(const u16* g, const u16* s) {
  __builtin_amdgcn_global_load_lds(
      (const __attribute__((address_space(1))) void*)g,
      (__attribute__((address_space(3))) void*)s, 16, 0, 0);
}

__device__ __forceinline__ u16 f2bf(float x) {
  __hip_bfloat16 h = __float2bfloat16(x);
  return *reinterpret_cast<u16*>(&h);
}
__device__ __forceinline__ float bf2f(u16 x) {
  __hip_bfloat16 h = *reinterpret_cast<__hip_bfloat16*>(&x);
  return __bfloat162float(h);
}

// ------------------------------------------------------------------
// transpose helper: W[K=1024][N] fp32 -> Wt[N][1024] bf16, one 32x32 tile
// ------------------------------------------------------------------
__device__ __forceinline__ void transpose_step(
    const float* __restrict__ W, u16* __restrict__ Wt, int N, int nbx,
    int local, int t, float (*tile)[33]) {
  int bx = local % nbx, by = local / nbx;
  int n0 = bx * 32, k0 = by * 32;
  int r = t >> 3, c4 = (t & 7) * 4;
  float4 v = *reinterpret_cast<const float4*>(&W[(size_t)(k0 + r) * N + n0 + c4]);
  tile[r][c4 + 0] = v.x;
  tile[r][c4 + 1] = v.y;
  tile[r][c4 + 2] = v.z;
  tile[r][c4 + 3] = v.w;
  __syncthreads();
  u16 o[4];
#pragma unroll
  for (int i = 0; i < 4; ++i) o[i] = f2bf(tile[c4 + i][r]);
  *reinterpret_cast<uint2*>(&Wt[(size_t)(n0 + r) * 1024 + k0 + c4]) =
      *reinterpret_cast<const uint2*>(o);
}

// ------------------------------------------------------------------
// fused prep: rope tables | X cvt | WQ,WV,WK -> WQVKt[9216][1024] |
//             WO -> WOt | bias concat [bQ;bV;bK]
// ------------------------------------------------------------------
__global__ __launch_bounds__(256) void prep_kernel(
    const float* __restrict__ X, const float* __restrict__ WQ,
    const float* __restrict__ WK, const float* __restrict__ WV,
    const float* __restrict__ WO, const float* __restrict__ bQ,
    const float* __restrict__ bV, const float* __restrict__ bK,
    u16* __restrict__ Xb, u16* __restrict__ WQVKt, u16* __restrict__ WOt,
    float* __restrict__ bQVK, float* __restrict__ ctab, float* __restrict__ stab)
{
  __shared__ float tile[32][33];
  const int blk = blockIdx.x, t = threadIdx.x;
  if (blk < 128) {                       // rope tables (32768)
    int id = blk * 256 + t;
    int tt = id >> 5, p = id & 31;
    float invf = exp2f(-LOG2_10000 * (float)(2 * p) * (1.0f / 64.0f));
    float ang = (float)tt * invf;
    float sn, cs;
    sincosf(ang, &sn, &cs);
    ctab[id] = cs;
    stab[id] = sn;
  } else if (blk < 1152) {               // X fp32 -> bf16 (262144 x8)
    int i = (blk - 128) * 256 + t;
    float4 a = reinterpret_cast<const float4*>(X)[2 * i];
    float4 b = reinterpret_cast<const float4*>(X)[2 * i + 1];
    u16 o[8] = {f2bf(a.x), f2bf(a.y), f2bf(a.z), f2bf(a.w),
                f2bf(b.x), f2bf(b.y), f2bf(b.z), f2bf(b.w)};
    reinterpret_cast<uint4*>(Xb)[i] = *reinterpret_cast<const uint4*>(o);
  } else if (blk < 5248) {
    transpose_step(WQ, WQVKt, 4096, 128, blk - 1152, t, tile);
  } else if (blk < 9344) {
    transpose_step(WV, WQVKt + (size_t)4096 * 1024, 4096, 128, blk - 5248, t, tile);
  } else if (blk < 10368) {
    transpose_step(WK, WQVKt + (size_t)8192 * 1024, 1024, 32, blk - 9344, t, tile);
  } else if (blk < 11392) {
    transpose_step(WO, WOt, 1024, 32, blk - 10368, t, tile);
  } else {                               // bias concat (9216)
    int id = (blk - 11392) * 256 + t;
    if (id < 9216)
      bQVK[id] = (id < 4096) ? bQ[id] : (id < 8192) ? bV[id - 4096] : bK[id - 8192];
  }
}

// ------------------------------------------------------------------
// QV GEMM: 256x128 tile, BK=32, 3 LDS slots (72 KB -> 2 blocks/CU),
// depth-1 prefetch, counted vmcnt(3), ONE barrier per K-tile (WAR safe
// with 3 slots: slot (t+1)%3 last read in iter t-2, separated by
// barrier t-1). Same verified swizzle chunk^=(row>>1)&3 and skeleton
// as the R8 kernel. Grid 512 = 2 blocks/CU -> inter-block TLP hides
// barrier drains (m114 mechanism). XCD map: each XCD 8 bx x all by.
// ------------------------------------------------------------------
__global__ __launch_bounds__(512, 4) void gemm_qv_kernel(
    const u16* __restrict__ Ab, const u16* __restrict__ Bt,
    const float* __restrict__ bias, u16* __restrict__ Cqv)
{
  __shared__ __align__(16) u16 sA[3][256 * 32];
  __shared__ __align__(16) u16 sB[3][128 * 32];

  const int tid = threadIdx.x;
  const int lane = tid & 63;
  const int w = tid >> 6;
  const int wm = w >> 2, wn = w & 3;
  const int l15 = lane & 15, l4 = lane >> 4;

  const int orig = blockIdx.x;          // 512
  const int xcd = orig & 7, j = orig >> 3;      // j in [0,64)
  const int bx = xcd * 8 + (j & 7);             // [0,64)
  const int by = j >> 3;                        // [0,8)
  const int m0 = by * 256, n0 = bx * 128;

  // A staging: 1024 chunks (2/thread: tid, tid+512); B: 512 chunks (1/thread)
  const int rA0 = tid >> 2, cA = tid & 3;
  const int scA = cA ^ ((rA0 >> 1) & 3);        // (rA0+128)>>1 preserves &3
  const int rB0 = tid >> 2;
  const int scB = cA ^ ((rB0 >> 1) & 3);
  const u16* aA0 = Ab + (size_t)(m0 + rA0) * 1024 + 8 * scA;
  const u16* aA1 = Ab + (size_t)(m0 + rA0 + 128) * 1024 + 8 * scA;
  const u16* aB0 = Bt + (size_t)(n0 + rB0) * 1024 + 8 * scB;

  const int cp = l4 ^ ((l15 >> 1) & 3);

  f32x4 acc[8][2];
#pragma unroll
  for (int i = 0; i < 8; ++i)
#pragma unroll
    for (int jn = 0; jn < 2; ++jn) acc[i][jn] = (f32x4){0.f, 0.f, 0.f, 0.f};

#define STAGE(t)                                                               \
  {                                                                            \
    const int sl = (t) % 3;                                                    \
    const int ko = (t) * 32;                                                   \
    gload16(aA0 + ko, &sA[sl][tid * 8]);                                       \
    gload16(aA1 + ko, &sA[sl][4096 + tid * 8]);                                \
    gload16(aB0 + ko, &sB[sl][tid * 8]);                                       \
  }

  STAGE(0);
#pragma unroll 1
  for (int t = 0; t < 32; ++t) {
    if (t + 1 < 32) {
      STAGE(t + 1);
      asm volatile("s_waitcnt vmcnt(3)" ::: "memory");
    } else {
      asm volatile("s_waitcnt vmcnt(0)" ::: "memory");
    }
    __builtin_amdgcn_sched_barrier(0);
    __builtin_amdgcn_s_barrier();
    __builtin_amdgcn_sched_barrier(0);

    const u16* tA = sA[t % 3];
    const u16* tB = sB[t % 3];

    bf16x8 bf[2];
#pragma unroll
    for (int n = 0; n < 2; ++n) {
      int row = wn * 32 + n * 16 + l15;
      bf[n] = *reinterpret_cast<const bf16x8*>(&tB[row * 32 + cp * 8]);
    }
    bf16x8 af[8];
#pragma unroll
    for (int m = 0; m < 8; ++m) {
      int row = wm * 128 + m * 16 + l15;
      af[m] = *reinterpret_cast<const bf16x8*>(&tA[row * 32 + cp * 8]);
    }
    __builtin_amdgcn_s_setprio(1);
#pragma unroll
    for (int m = 0; m < 8; ++m)
#pragma unroll
      for (int n = 0; n < 2; ++n)
        acc[m][n] = __builtin_amdgcn_mfma_f32_16x16x32_bf16(
            af[m], bf[n], acc[m][n], 0, 0, 0);
    __builtin_amdgcn_s_setprio(0);
    // WAR: STAGE(t+2) (next iter) writes slot (t+2)%3, last read in iter
    // t-1, and every wave passed barrier t before issuing it.
  }
#undef STAGE

#pragma unroll
  for (int n = 0; n < 2; ++n) {
    int col = n0 + wn * 32 + n * 16 + l15;
    float bv = bias[col];
#pragma unroll
    for (int mf = 0; mf < 8; ++mf) {
#pragma unroll
      for (int r = 0; r < 4; ++r) {
        int row = m0 + wm * 128 + mf * 16 + l4 * 4 + r;
        Cqv[(size_t)row * 8192 + col] = f2bf(acc[mf][n][r] + bv);
      }
    }
  }
}

// ------------------------------------------------------------------
// 64x64-tile bf16 MFMA GEMM, BK=64, double-buffered, ONE raw barrier
// per K-step + counted vmcnt(4). LDS rows 128B with chunk^(row&7)
// swizzle (2-way bank aliasing = free).
// ------------------------------------------------------------------
template <bool BF16OUT>
__global__ __launch_bounds__(256) void gemm64_kernel(
    const u16* __restrict__ Ab, const u16* __restrict__ Bt,
    const float* __restrict__ bias, void* __restrict__ Cv,
    int M, int N, int K)
{
  __shared__ __align__(16) u16 sA[2][64 * 64];
  __shared__ __align__(16) u16 sB[2][64 * 64];
  const int tid = threadIdx.x;
  const int lane = tid & 63;
  const int wv = tid >> 6;
  const int wm = wv >> 1, wn = wv & 1;
  const int l15 = lane & 15, l4 = lane >> 4;
  const int m0 = blockIdx.y * 64, n0 = blockIdx.x * 64;

  f32x4 acc[2][2];
#pragma unroll
  for (int i = 0; i < 2; ++i)
#pragma unroll
    for (int j = 0; j < 2; ++j) acc[i][j] = (f32x4){0.f, 0.f, 0.f, 0.f};

  const int r0s = tid >> 3,         c0s = tid & 7;
  const int r1s = (256 + tid) >> 3, c1s = (256 + tid) & 7;
  const int sc0 = c0s ^ (r0s & 7);
  const int sc1 = c1s ^ (r1s & 7);
  const u16* aA0 = Ab + (size_t)(m0 + r0s) * K + 8 * sc0;
  const u16* aA1 = Ab + (size_t)(m0 + r1s) * K + 8 * sc1;
  const u16* aB0 = Bt + (size_t)(n0 + r0s) * K + 8 * sc0;
  const u16* aB1 = Bt + (size_t)(n0 + r1s) * K + 8 * sc1;

  gload16(aA0, &sA[0][tid * 8]);
  gload16(aA1, &sA[0][2048 + tid * 8]);
  gload16(aB0, &sB[0][tid * 8]);
  gload16(aB1, &sB[0][2048 + tid * 8]);

  const int niter = K >> 6;
#pragma unroll 1
  for (int it = 0; it < niter; ++it) {
    const int buf = it & 1;
    __builtin_amdgcn_s_barrier();
    if (it + 1 < niter) {
      const int ko = (it + 1) * 64;
      gload16(aA0 + ko, &sA[buf ^ 1][tid * 8]);
      gload16(aA1 + ko, &sA[buf ^ 1][2048 + tid * 8]);
      gload16(aB0 + ko, &sB[buf ^ 1][tid * 8]);
      gload16(aB1 + ko, &sB[buf ^ 1][2048 + tid * 8]);
      asm volatile("s_waitcnt vmcnt(4)" ::: "memory");
    } else {
      asm volatile("s_waitcnt vmcnt(0)" ::: "memory");
    }
    __builtin_amdgcn_sched_barrier(0);
    bf16x8 af[2][2], bfv[2][2];
#pragma unroll
    for (int kk = 0; kk < 2; ++kk) {
#pragma unroll
      for (int mi = 0; mi < 2; ++mi) {
        int row = wm * 32 + mi * 16 + l15;
        int cs = (kk * 4 + l4) ^ (row & 7);
        af[mi][kk] = *reinterpret_cast<const bf16x8*>(&sA[buf][row * 64 + cs * 8]);
      }
#pragma unroll
      for (int ni = 0; ni < 2; ++ni) {
        int row = wn * 32 + ni * 16 + l15;
        int cs = (kk * 4 + l4) ^ (row & 7);
        bfv[ni][kk] = *reinterpret_cast<const bf16x8*>(&sB[buf][row * 64 + cs * 8]);
      }
    }
#pragma unroll
    for (int kk = 0; kk < 2; ++kk)
#pragma unroll
      for (int mi = 0; mi < 2; ++mi)
#pragma unroll
        for (int ni = 0; ni < 2; ++ni)
          acc[mi][ni] = __builtin_amdgcn_mfma_f32_16x16x32_bf16(
              af[mi][kk], bfv[ni][kk], acc[mi][ni], 0, 0, 0);
  }

#pragma unroll
  for (int mi = 0; mi < 2; ++mi)
#pragma unroll
    for (int ni = 0; ni < 2; ++ni) {
      int col = n0 + wn * 32 + ni * 16 + l15;
      float bv = bias[col];
#pragma unroll
      for (int r = 0; r < 4; ++r) {
        int row = m0 + wm * 32 + mi * 16 + l4 * 4 + r;
        float val = acc[mi][ni][r] + bv;
        size_t idx = (size_t)row * N + col;
        if (BF16OUT) ((u16*)Cv)[idx] = f2bf(val);
        else ((float*)Cv)[idx] = val;
      }
    }
}

// ------------------------------------------------------------------
// merged: q/k transform (blocks < 20480) + vsum partials (128 blocks).
// ------------------------------------------------------------------
__global__ __launch_bounds__(256) void qkvt_kernel(
    u16* __restrict__ QVbf, u16* __restrict__ Kbf,
    const float* __restrict__ ctab, const float* __restrict__ stab,
    float* __restrict__ part)
{
  const int blk = blockIdx.x;
  if (blk < 20480) {
    const int rid  = blk * 8 + (threadIdx.x >> 5);
    const int lane = threadIdx.x & 63;
    const int p    = lane & 31;
    const int gb   = lane & 32;

    u16* row;
    int t;
    const bool isQ = rid < 131072;
    if (isQ) {
      int h = rid & 63, bt = rid >> 6;
      t = bt & 1023;
      row = QVbf + (size_t)bt * 8192 + h * 64;
    } else {
      int r2 = rid - 131072;
      int hsL = r2 & 15, bt = r2 >> 4;
      t = bt & 1023;
      row = Kbf + (size_t)bt * 1024 + hsL * 64;
    }

    u32 v = reinterpret_cast<const u32*>(row)[p];
    float x1 = bf2f((u16)v), x2 = bf2f((u16)(v >> 16));
    float cs = ctab[t * 32 + p], sn = stab[t * 32 + p];

    float o_lo, o_hi;
    if (isQ) {
      float ss = x1 * x1 + x2 * x2;
      ss += __shfl_xor(ss, 1, 64);
      ss += __shfl_xor(ss, 2, 64);
      ss += __shfl_xor(ss, 4, 64);
      ss += __shfl_xor(ss, 8, 64);
      ss += __shfl_xor(ss, 16, 64);
      float rs = rsqrtf(ss * (1.0f / 64.0f) + 1.1920929e-7f);
      float xn1 = x1 * rs, xn2 = x2 * rs;
      o_lo = xn1 * cs - xn2 * sn;
      o_hi = xn1 * sn + xn2 * cs;
    } else {
      float xr1 = x1 * cs - x2 * sn;
      float xr2 = x1 * sn + x2 * cs;
      float ss = xr1 * xr1 + xr2 * xr2;
      ss += __shfl_xor(ss, 1, 64);
      ss += __shfl_xor(ss, 2, 64);
      ss += __shfl_xor(ss, 4, 64);
      ss += __shfl_xor(ss, 8, 64);
      ss += __shfl_xor(ss, 16, 64);
      float rs = rsqrtf(ss);
      o_lo = xr1 * rs;
      o_hi = xr2 * rs;
    }

    int m = (2 * p) & 31;
    float slo0 = __shfl(o_lo, gb + m, 64);
    float slo1 = __shfl(o_lo, gb + m + 1, 64);
    float shi0 = __shfl(o_hi, gb + m, 64);
    float shi1 = __shfl(o_hi, gb + m + 1, 64);
    float e0 = (p < 16) ? slo0 : shi0;
    float e1 = (p < 16) ? slo1 : shi1;
    reinterpret_cast<u32*>(row)[p] = (u32)f2bf(e0) | ((u32)f2bf(e1) << 16);
  } else {
    int vb = blk - 20480;               // 0..127: b*64 + ch
    int b = vb >> 6, ch = vb & 63;
    const u16* base = QVbf + (size_t)(b * 1024 + ch * 16) * 8192 + 4096;
#pragma unroll
    for (int g = 0; g < 2; ++g) {
      int c0 = (threadIdx.x + g * 256) * 8;
      float s[8] = {0.f, 0.f, 0.f, 0.f, 0.f, 0.f, 0.f, 0.f};
#pragma unroll 4
      for (int r = 0; r < 16; ++r) {
        bf16x8 v = *reinterpret_cast<const bf16x8*>(&base[(size_t)r * 8192 + c0]);
#pragma unroll
        for (int e = 0; e < 8; ++e) s[e] += bf2f((u16)v[e]);
      }
      float* dst = &part[(size_t)vb * 4096 + c0];
#pragma unroll
      for (int e = 0; e < 8; ++e) dst[e] = s[e];
    }
  }
}

__global__ __launch_bounds__(256) void vsum_reduce_kernel(
    const float* __restrict__ part, float* __restrict__ Vsum) {
  int id = blockIdx.x * 256 + threadIdx.x;  // 8192
  int b = id >> 12, n = id & 4095;
  float s = 0.f;
#pragma unroll 8
  for (int ch = 0; ch < 64; ++ch) s += part[(size_t)(b * 64 + ch) * 4096 + n];
  Vsum[id] = s;
}

// ------------------------------------------------------------------
// MFMA banded attention, QBLK=64, 2-phase double-buffered K/V pipeline
// (R11/R14-proven structure with setprio around MFMA clusters).
// ------------------------------------------------------------------
__global__ __launch_bounds__(256) void attn_mfma_kernel(
    const u16* __restrict__ Qv, const u16* __restrict__ Kb,
    const float* __restrict__ Vsum, const float* __restrict__ sink,
    const float* __restrict__ vnull, u16* __restrict__ mctxb)
{
  __shared__ __align__(16) u16 sQ[64 * 64];
  __shared__ __align__(16) u16 sK[2][64 * 64];
  __shared__ __align__(16) u16 sVt[2][64 * 64];
  __shared__ __align__(16) u16 sP[64 * 64];

  int blk = blockIdx.x;
  blk = (blk & 7) * 64 + (blk >> 3);
  const int qt  = blk & 15;
  const int hs  = (blk >> 4) & 15;
  const int b   = blk >> 8;
  const int qt0 = qt * 64;

  const int tid  = threadIdx.x;
  const int lane = tid & 63;
  const int wv   = tid >> 6;
  const int l15  = lane & 15;
  const int l4   = lane >> 4;
  const int qr0  = tid >> 3, qi0 = tid & 7;
  const int qr1  = qr0 + 32;
  const int vjp  = tid & 31, vdg = tid >> 5;
  const int qrow = wv * 16 + l15;

  constexpr int HCFG[4] = {16, 128, 128, 512};
  constexpr int GCFG[4] = {0, 16, 0, 144};

  f32x4 macc[4];
#pragma unroll
  for (int i = 0; i < 4; ++i) macc[i] = (f32x4){0.f, 0.f, 0.f, 0.f};

#pragma unroll 1
  for (int br = 0; br < 4; ++br) {
    const int h = br * 16 + hs;
    const int hmax = HCFG[br], g = GCFG[br];
    int klo = qt0 - (hmax - 1); if (klo < 0) klo = 0;
    int khi = qt0 + 63 - g;     if (khi > 1023) khi = 1023;
    const int nc = (khi >= klo) ? ((khi - klo) / 64 + 1) : 0;

    gload16(Qv + (size_t)(b * 1024 + qt0 + qr0) * 8192 + h * 64 + 8 * (qi0 ^ (qr0 & 7)),
            sQ + (size_t)wv * 512);
    gload16(Qv + (size_t)(b * 1024 + qt0 + qr1) * 8192 + h * 64 + 8 * (qi0 ^ (qr1 & 7)),
            sQ + 2048 + (size_t)wv * 512);
    bf16x8 va, vb;
    if (nc > 0) {
      int ja0 = klo + qr0; if (ja0 > 1023) ja0 = 1023;
      int ja1 = klo + qr1; if (ja1 > 1023) ja1 = 1023;
      gload16(Kb + (size_t)(b * 1024 + ja0) * 1024 + hs * 64 + 8 * (qi0 ^ (qr0 & 7)),
              sK[0] + (size_t)wv * 512);
      gload16(Kb + (size_t)(b * 1024 + ja1) * 1024 + hs * 64 + 8 * (qi0 ^ (qr1 & 7)),
              sK[0] + 2048 + (size_t)wv * 512);
      int jva = klo + 2 * vjp, jvb = jva + 1;
      if (jva > 1023) jva = 1023;
      if (jvb > 1023) jvb = 1023;
      va = *reinterpret_cast<const bf16x8*>(
          &Qv[(size_t)(b * 1024 + jva) * 8192 + 4096 + h * 64 + vdg * 8]);
      vb = *reinterpret_cast<const bf16x8*>(
          &Qv[(size_t)(b * 1024 + jvb) * 8192 + 4096 + h * 64 + vdg * 8]);
    }
    asm volatile("s_waitcnt vmcnt(0)" ::: "memory");
    __builtin_amdgcn_sched_barrier(0);
    if (nc > 0) {
#pragma unroll
      for (int e = 0; e < 8; ++e) {
        int d = vdg * 8 + e;
        u32 pack = (u32)(u16)va[e] | ((u32)(u16)vb[e] << 16);
        *reinterpret_cast<u32*>(
            (char*)sVt[0] + d * 128 + ((4 * vjp) ^ ((d & 7) << 4))) = pack;
      }
    }
    asm volatile("s_waitcnt lgkmcnt(0)" ::: "memory");
    __builtin_amdgcn_sched_barrier(0);
    __builtin_amdgcn_s_barrier();

    bf16x8 afQ[2];
#pragma unroll
    for (int kh = 0; kh < 2; ++kh) {
      int cs = (4 * kh + l4) ^ (l15 & 7);
      afQ[kh] = *reinterpret_cast<const bf16x8*>(&sQ[qrow * 64 + cs * 8]);
    }

    f32x4 outv[4];
#pragma unroll
    for (int i = 0; i < 4; ++i) outv[i] = (f32x4){0.f, 0.f, 0.f, 0.f};
    float zacc[4] = {0.f, 0.f, 0.f, 0.f};

    int buf = 0;
#pragma unroll 1
    for (int c = 0; c < nc; ++c) {
      const int j0 = klo + c * 64;
      const bool nxt = (c + 1 < nc);
      if (nxt) {
        int j0n = j0 + 64;
        int ja0 = j0n + qr0; if (ja0 > 1023) ja0 = 1023;
        int ja1 = j0n + qr1; if (ja1 > 1023) ja1 = 1023;
        gload16(Kb + (size_t)(b * 1024 + ja0) * 1024 + hs * 64 + 8 * (qi0 ^ (qr0 & 7)),
                sK[buf ^ 1] + (size_t)wv * 512);
        gload16(Kb + (size_t)(b * 1024 + ja1) * 1024 + hs * 64 + 8 * (qi0 ^ (qr1 & 7)),
                sK[buf ^ 1] + 2048 + (size_t)wv * 512);
        int jva = j0n + 2 * vjp, jvb = jva + 1;
        if (jva > 1023) jva = 1023;
        if (jvb > 1023) jvb = 1023;
        va = *reinterpret_cast<const bf16x8*>(
            &Qv[(size_t)(b * 1024 + jva) * 8192 + 4096 + h * 64 + vdg * 8]);
        vb = *reinterpret_cast<const bf16x8*>(
            &Qv[(size_t)(b * 1024 + jvb) * 8192 + 4096 + h * 64 + vdg * 8]);
      }
      f32x4 sfr[4];
      __builtin_amdgcn_s_setprio(1);
#pragma unroll
      for (int jt = 0; jt < 4; ++jt) {
        int krow = jt * 16 + l15;
        f32x4 acc = (f32x4){0.f, 0.f, 0.f, 0.f};
#pragma unroll
        for (int kh = 0; kh < 2; ++kh) {
          int cs = (4 * kh + l4) ^ (l15 & 7);
          bf16x8 bk = *reinterpret_cast<const bf16x8*>(&sK[buf][krow * 64 + cs * 8]);
          acc = __builtin_amdgcn_mfma_f32_16x16x32_bf16(afQ[kh], bk, acc, 0, 0, 0);
        }
        sfr[jt] = acc;
      }
      __builtin_amdgcn_s_setprio(0);
#pragma unroll
      for (int jt = 0; jt < 4; ++jt) {
        int jloc = jt * 16 + l15;
        int jabs = j0 + jloc;
#pragma unroll
        for (int r = 0; r < 4; ++r) {
          int q_r = wv * 16 + l4 * 4 + r;
          int dist = (qt0 + q_r) - jabs;
          bool inband = (dist >= g) & (dist < hmax) & (jabs < 1024);
          float pv = inband ? (__expf(sfr[jt][r]) - 1.0f) : 0.0f;
          zacc[r] += pv;
          *reinterpret_cast<u16*>(
              (char*)sP + q_r * 128 + ((2 * jloc) ^ ((q_r & 7) << 4))) = f2bf(pv);
        }
      }
      asm volatile("s_waitcnt lgkmcnt(0)" ::: "memory");
      __builtin_amdgcn_sched_barrier(0);
      bf16x8 afP[2];
#pragma unroll
      for (int kh = 0; kh < 2; ++kh) {
        int cs = (4 * kh + l4) ^ (l15 & 7);
        afP[kh] = *reinterpret_cast<const bf16x8*>(&sP[qrow * 64 + cs * 8]);
      }
      __builtin_amdgcn_s_setprio(1);
#pragma unroll
      for (int dt = 0; dt < 4; ++dt) {
        int drow = dt * 16 + l15;
#pragma unroll
        for (int kh = 0; kh < 2; ++kh) {
          int cs = (4 * kh + l4) ^ (l15 & 7);
          bf16x8 bv = *reinterpret_cast<const bf16x8*>(&sVt[buf][drow * 64 + cs * 8]);
          outv[dt] = __builtin_amdgcn_mfma_f32_16x16x32_bf16(afP[kh], bv, outv[dt], 0, 0, 0);
        }
      }
      __builtin_amdgcn_s_setprio(0);
      if (nxt) {
#pragma unroll
        for (int e = 0; e < 8; ++e) {
          int d = vdg * 8 + e;
          u32 pack = (u32)(u16)va[e] | ((u32)(u16)vb[e] << 16);
          *reinterpret_cast<u32*>(
              (char*)sVt[buf ^ 1] + d * 128 + ((4 * vjp) ^ ((d & 7) << 4))) = pack;
        }
      }
      asm volatile("s_waitcnt vmcnt(0) lgkmcnt(0)" ::: "memory");
      __builtin_amdgcn_sched_barrier(0);
      __builtin_amdgcn_s_barrier();
      buf ^= 1;
    }

#pragma unroll
    for (int r = 0; r < 4; ++r) {
      zacc[r] += __shfl_xor(zacc[r], 1, 64);
      zacc[r] += __shfl_xor(zacc[r], 2, 64);
      zacc[r] += __shfl_xor(zacc[r], 4, 64);
      zacc[r] += __shfl_xor(zacc[r], 8, 64);
    }
    float es = __expf(tanhf(sink[h]));
#pragma unroll
    for (int dt = 0; dt < 4; ++dt) {
      int d = dt * 16 + l15;
      float vs = Vsum[(size_t)b * 4096 + h * 64 + d];
      float vn = vnull[h * 64 + d];
#pragma unroll
      for (int r = 0; r < 4; ++r) {
        float invZ = 1.0f / (1024.0f + zacc[r] + es);
        macc[dt][r] += (outv[dt][r] + vs + es * vn) * invZ;
      }
    }
  }

#pragma unroll
  for (int dt = 0; dt < 4; ++dt) {
#pragma unroll
    for (int r = 0; r < 4; ++r) {
      int q_r = wv * 16 + l4 * 4 + r;
      mctxb[(size_t)(b * 1024 + qt0 + q_r) * 1024 + hs * 64 + dt * 16 + l15] =
          f2bf(0.25f * macc[dt][r]);
    }
  }
}

extern "C" void kernel_launch(void* const* d_in, const int* in_sizes, int n_in,
                              void* d_out, int out_size, void* d_ws, size_t ws_size,
                              hipStream_t stream) {
  (void)in_sizes; (void)n_in; (void)out_size; (void)ws_size;
  const float* X    = (const float*)d_in[0];
  const float* WQ   = (const float*)d_in[1];
  const float* bQ   = (const float*)d_in[2];
  const float* WK   = (const float*)d_in[3];
  const float* bK   = (const float*)d_in[4];
  const float* WV   = (const float*)d_in[5];
  const float* bV   = (const float*)d_in[6];
  const float* WO   = (const float*)d_in[7];
  const float* bO   = (const float*)d_in[8];
  const float* sink = (const float*)d_in[9];
  const float* vnul = (const float*)d_in[10];
  float* Y = (float*)d_out;

  char* p = (char*)d_ws;
  u16*   Xb    = (u16*)p;   p += (size_t)2048 * 1024 * 2;   //  4 MB
  u16*   WQVKt = (u16*)p;   p += (size_t)9216 * 1024 * 2;   // 18 MB
  u16*   WOt   = (u16*)p;   p += (size_t)1024 * 1024 * 2;   //  2 MB
  u16*   QVbf  = (u16*)p;   p += (size_t)2048 * 8192 * 2;   // 32 MB
  u16*   Kbf   = (u16*)p;   p += (size_t)2048 * 1024 * 2;   //  4 MB
  u16*   mctxb = (u16*)p;   p += (size_t)2048 * 1024 * 2;   //  4 MB
  float* Vsum  = (float*)p; p += (size_t)2 * 4096 * 4;      // 32 KB
  float* vpart = (float*)p; p += (size_t)128 * 4096 * 4;    //  2 MB
  float* bQVK  = (float*)p; p += (size_t)9216 * 4;          //  36 KB
  float* ctab  = (float*)p; p += (size_t)32768 * 4;         // 128 KB
  float* stab  = (float*)p; p += (size_t)32768 * 4;         // 128 KB

  dim3 blk(256);
  prep_kernel<<<11428, blk, 0, stream>>>(X, WQ, WK, WV, WO, bQ, bV, bK,
                                         Xb, WQVKt, WOt, bQVK, ctab, stab);

  gemm_qv_kernel<<<512, dim3(512), 0, stream>>>(Xb, WQVKt, bQVK, QVbf);
  gemm64_kernel<true><<<dim3(16, 32), blk, 0, stream>>>(
      Xb, WQVKt + (size_t)8192 * 1024, bQVK + 8192, Kbf, 2048, 1024, 1024);

  qkvt_kernel<<<20608, blk, 0, stream>>>(QVbf, Kbf, ctab, stab, vpart);
  vsum_reduce_kernel<<<32, blk, 0, stream>>>(vpart, Vsum);

  attn_mfma_kernel<<<512, blk, 0, stream>>>(QVbf, Kbf, Vsum, sink, vnul, mctxb);

  gemm64_kernel<false><<<dim3(16, 32), blk, 0, stream>>>(mctxb, WOt, bO, Y, 2048, 1024, 1024);
}